// Round 1
// baseline (45.558 us; speedup 1.0000x reference)
//
#include <hip/hip_runtime.h>

namespace {
constexpr int IMG = 256;
constexpr int NPTS = 320;
constexpr int NSEG = 8;
constexpr int SEGLEN = NPTS / NSEG;     // 40
constexpr float MIN_D = 3.0f;
constexpr float STEP = 6.0f / 319.0f;   // linspace(3,9,320) step
constexpr float EPS_EA = 1e-10f;
constexpr float EPS_MIN = 1e-8f;
constexpr float SCALING = 0.1f;
}

// Block: (64 w-lanes, 8 ray-segments). Each thread integrates 40 depth steps of
// one pixel's ray; wave 0 combines the 8 segment partials via the product-scan
// identity: rgb = sum_s S_s * prod_{t<s} P_t ; opa = 1 - prod_s Q_s.
__global__ __launch_bounds__(512)
void render_kernel(const float* __restrict__ vol,
                   const float* __restrict__ cam_rot,
                   const float* __restrict__ cam_pos,
                   float* __restrict__ gray_out,
                   float* __restrict__ maxp)
{
    __shared__ float Ssh[NSEG][64];
    __shared__ float Psh[NSEG][64];
    __shared__ float Qsh[NSEG][64];

    const int tx  = threadIdx.x;
    const int seg = threadIdx.y;
    const int w   = blockIdx.x * 64 + tx;
    const int h   = blockIdx.y;

    const float gx = -1.0f + 2.0f * (float)w * (1.0f / 255.0f);
    const float gy = -1.0f + 2.0f * (float)h * (1.0f / 255.0f);
    const float dcx = gx * (1.0f / 3.0f);
    const float dcy = gy * (1.0f / 3.0f);

    // dir_world = R * dir_cam  (dir_cam.z == 1)
    const float dx = cam_rot[0] * dcx + cam_rot[1] * dcy + cam_rot[2];
    const float dy = cam_rot[3] * dcx + cam_rot[4] * dcy + cam_rot[5];
    const float dz = cam_rot[6] * dcx + cam_rot[7] * dcy + cam_rot[8];
    const float cx = cam_pos[0], cy = cam_pos[1], cz = cam_pos[2];

    // half = (2/256)*255/2 = 255/256; f = (p/half + 1)*127.5 = p*128 + 127.5
    float S = 0.0f;   // sum dens*feat*A   (A = exclusive absorb within segment)
    float A = 1.0f;   // prod (1+eps - dens)
    float Q = 1.0f;   // prod (1 - dens)

    const int k0 = seg * SEGLEN;
    #pragma unroll 1
    for (int k = k0; k < k0 + SEGLEN; ++k) {
        const float d  = fmaf((float)k, STEP, MIN_D);
        const float px = fmaf(dx, d, cx);
        const float py = fmaf(dy, d, cy);
        const float pz = fmaf(dz, d, cz);
        const float fx = fmaf(px, 128.0f, 127.5f);
        const float fy = fmaf(py, 128.0f, 127.5f);
        const float fz = fmaf(pz, 128.0f, 127.5f);

        // Entirely outside coverage window on any axis -> dens=0, feat=0.
        if (fx <= -1.0f || fx >= 256.0f || fy <= -1.0f || fy >= 256.0f ||
            fz <= -1.0f || fz >= 256.0f) {
            A *= (1.0f + EPS_EA);
            continue;
        }

        const float fx0 = floorf(fx), fy0 = floorf(fy), fz0 = floorf(fz);
        const int x0 = (int)fx0, y0 = (int)fy0, z0 = (int)fz0;
        const float wx = fx - fx0, wy = fy - fy0, wz = fz - fz0;

        float dens, feat;
        if ((unsigned)x0 < 255u && (unsigned)y0 < 255u && (unsigned)z0 < 255u) {
            // Fully interior: coverage == 1 on all axes -> dens = SCALING.
            const int base = (z0 << 16) + (y0 << 8) + x0;
            const float c000 = vol[base];
            const float c001 = vol[base + 1];
            const float c010 = vol[base + 256];
            const float c011 = vol[base + 257];
            const float c100 = vol[base + 65536];
            const float c101 = vol[base + 65537];
            const float c110 = vol[base + 65536 + 256];
            const float c111 = vol[base + 65536 + 257];
            const float f00 = fmaf(wx, c001 - c000, c000);
            const float f01 = fmaf(wx, c011 - c010, c010);
            const float f10 = fmaf(wx, c101 - c100, c100);
            const float f11 = fmaf(wx, c111 - c110, c110);
            const float f0  = fmaf(wy, f01 - f00, f00);
            const float f1  = fmaf(wy, f11 - f10, f10);
            feat = fmaf(wz, f1 - f0, f0);
            dens = SCALING;
        } else {
            // Border: zero-pad corners, per-axis coverage.
            const int x1 = x0 + 1, y1 = y0 + 1, z1 = z0 + 1;
            const bool bx0 = (unsigned)x0 < 256u, bx1 = (unsigned)x1 < 256u;
            const bool by0 = (unsigned)y0 < 256u, by1 = (unsigned)y1 < 256u;
            const bool bz0 = (unsigned)z0 < 256u, bz1 = (unsigned)z1 < 256u;
            const int xc0 = min(max(x0, 0), 255), xc1 = min(max(x1, 0), 255);
            const int yc0 = min(max(y0, 0), 255), yc1 = min(max(y1, 0), 255);
            const int zc0 = min(max(z0, 0), 255), zc1 = min(max(z1, 0), 255);
            const int zy00 = (zc0 << 16) + (yc0 << 8);
            const int zy01 = (zc0 << 16) + (yc1 << 8);
            const int zy10 = (zc1 << 16) + (yc0 << 8);
            const int zy11 = (zc1 << 16) + (yc1 << 8);
            const float c000 = (bz0 && by0 && bx0) ? vol[zy00 + xc0] : 0.0f;
            const float c001 = (bz0 && by0 && bx1) ? vol[zy00 + xc1] : 0.0f;
            const float c010 = (bz0 && by1 && bx0) ? vol[zy01 + xc0] : 0.0f;
            const float c011 = (bz0 && by1 && bx1) ? vol[zy01 + xc1] : 0.0f;
            const float c100 = (bz1 && by0 && bx0) ? vol[zy10 + xc0] : 0.0f;
            const float c101 = (bz1 && by0 && bx1) ? vol[zy10 + xc1] : 0.0f;
            const float c110 = (bz1 && by1 && bx0) ? vol[zy11 + xc0] : 0.0f;
            const float c111 = (bz1 && by1 && bx1) ? vol[zy11 + xc1] : 0.0f;
            const float f00 = fmaf(wx, c001 - c000, c000);
            const float f01 = fmaf(wx, c011 - c010, c010);
            const float f10 = fmaf(wx, c101 - c100, c100);
            const float f11 = fmaf(wx, c111 - c110, c110);
            const float f0  = fmaf(wy, f01 - f00, f00);
            const float f1  = fmaf(wy, f11 - f10, f10);
            feat = fmaf(wz, f1 - f0, f0);
            const float covx = (1.0f - wx) * (float)bx0 + wx * (float)bx1;
            const float covy = (1.0f - wy) * (float)by0 + wy * (float)by1;
            const float covz = (1.0f - wz) * (float)bz0 + wz * (float)bz1;
            dens = SCALING * covx * covy * covz;
        }

        S = fmaf(dens * A, feat, S);       // weight uses exclusive absorb
        A *= (1.0f + EPS_EA - dens);
        Q *= (1.0f - dens);
    }

    Ssh[seg][tx] = S;
    Psh[seg][tx] = A;
    Qsh[seg][tx] = Q;
    __syncthreads();

    if (seg == 0) {
        float rgb = 0.0f, Ap = 1.0f, q = 1.0f;
        #pragma unroll
        for (int s = 0; s < NSEG; ++s) {
            rgb = fmaf(Ap, Ssh[s][tx], rgb);
            Ap *= Psh[s][tx];
            q  *= Qsh[s][tx];
        }
        const float gray = fmaf(3.0f, rgb, 1.0f - q) * 0.25f;
        gray_out[w * IMG + h] = gray;      // output is transposed (0,2,1)

        float m = gray;
        #pragma unroll
        for (int off = 32; off > 0; off >>= 1)
            m = fmaxf(m, __shfl_xor(m, off));
        if (tx == 0)
            atomicMax((int*)maxp, __float_as_int(m));   // gray >= 0
    }
}

__global__ void norm_kernel(float* __restrict__ out, const float* __restrict__ maxp)
{
    const int i = blockIdx.x * 256 + threadIdx.x;
    const float m = *maxp;
    out[i] = (out[i] + EPS_MIN) / (m + EPS_MIN);
}

extern "C" void kernel_launch(void* const* d_in, const int* in_sizes, int n_in,
                              void* d_out, int out_size, void* d_ws, size_t ws_size,
                              hipStream_t stream) {
    const float* vol     = (const float*)d_in[0];
    const float* cam_rot = (const float*)d_in[1];
    const float* cam_pos = (const float*)d_in[2];
    float* out  = (float*)d_out;
    float* maxp = (float*)d_ws;

    hipMemsetAsync(d_ws, 0, 4, stream);   // gray >= 0, so 0 is a safe identity

    dim3 block(64, NSEG);
    dim3 grid(IMG / 64, IMG);
    render_kernel<<<grid, block, 0, stream>>>(vol, cam_rot, cam_pos, out, maxp);
    norm_kernel<<<IMG, IMG, 0, stream>>>(out, maxp);
}

// Round 5
// 26.527 us; speedup vs baseline: 1.7174x; 1.7174x over previous
//
#include <hip/hip_runtime.h>

namespace {
constexpr int IMG = 256;
constexpr int NPTS = 320;
constexpr int NSEG = 16;
constexpr float MIN_D = 3.0f;
constexpr float STEP = 6.0f / 319.0f;   // linspace(3,9,320) step
constexpr float EPS_MIN = 1e-8f;
constexpr float SCALING = 0.1f;
}

// Block: (64 w-lanes, 16 ray-segments). Per ray we analytically intersect the
// sampling line with the coverage window (fx,fy,fz in (-1,256)), then split the
// ~107 active steps evenly over the 16 segment-threads. Wave 0 combines the
// segment partials via the product-scan identity:
//   rgb = sum_s S_s * prod_{t<s} A_t ; opa = 1 - prod_s A_s
// (in fp32, 1+1e-10-dens == 1-dens, so one absorb product serves both).
__global__ __launch_bounds__(1024)
void render_kernel(const float* __restrict__ vol,
                   const float* __restrict__ cam_rot,
                   const float* __restrict__ cam_pos,
                   float* __restrict__ gray_out)
{
    __shared__ float Ssh[NSEG][64];
    __shared__ float Ash[NSEG][64];

    const int tx  = threadIdx.x;
    const int seg = threadIdx.y;
    const int w   = blockIdx.x * 64 + tx;
    const int h   = blockIdx.y;

    const float gx = -1.0f + 2.0f * (float)w * (1.0f / 255.0f);
    const float gy = -1.0f + 2.0f * (float)h * (1.0f / 255.0f);
    const float dcx = gx * (1.0f / 3.0f);
    const float dcy = gy * (1.0f / 3.0f);

    // dir_world = R * dir_cam  (dir_cam.z == 1)
    const float dx = cam_rot[0] * dcx + cam_rot[1] * dcy + cam_rot[2];
    const float dy = cam_rot[3] * dcx + cam_rot[4] * dcy + cam_rot[5];
    const float dz = cam_rot[6] * dcx + cam_rot[7] * dcy + cam_rot[8];
    const float cx = cam_pos[0], cy = cam_pos[1], cz = cam_pos[2];

    // half = (2/256)*255/2 = 255/256; f = (p/half + 1)*127.5 = p*128 + 127.5
    // Analytic active range: need  -1 < f_a(k) < 256  on all axes, where
    // f_a(k) is linear in k. Widen by ±2 steps; keep per-step guard for bits.
    float klo_f = 0.0f, khi_f = (float)NPTS;
    {
        const float Aax[3] = { dx * (STEP * 128.0f),
                               dy * (STEP * 128.0f),
                               dz * (STEP * 128.0f) };
        const float Bax[3] = { fmaf(fmaf(dx, MIN_D, cx), 128.0f, 127.5f),
                               fmaf(fmaf(dy, MIN_D, cy), 128.0f, 127.5f),
                               fmaf(fmaf(dz, MIN_D, cz), 128.0f, 127.5f) };
        #pragma unroll
        for (int a = 0; a < 3; ++a) {
            const float A = Aax[a], B = Bax[a];
            if (fabsf(A) < 1e-12f) {
                if (B <= -1.0f || B >= 256.0f) { klo_f = 1.0f; khi_f = 0.0f; }
            } else {
                const float r = 1.0f / A;
                const float k1 = (-1.0f  - B) * r;
                const float k2 = (256.0f - B) * r;
                klo_f = fmaxf(klo_f, fminf(k1, k2));
                khi_f = fminf(khi_f, fmaxf(k1, k2));
            }
        }
    }
    const int klo = max(0, (int)floorf(klo_f) - 1);
    const int khi = min(NPTS, (int)ceilf(khi_f) + 2);
    const int n_active = max(0, khi - klo);

    const int per = (n_active + NSEG - 1) / NSEG;
    const int ks  = klo + seg * per;
    const int ke  = min(ks + per, khi);

    float S = 0.0f;   // sum dens*feat*A_excl within segment
    float A = 1.0f;   // prod (1 - dens) within segment

    #pragma unroll 2
    for (int k = ks; k < ke; ++k) {
        const float d  = fmaf((float)k, STEP, MIN_D);
        const float px = fmaf(dx, d, cx);
        const float py = fmaf(dy, d, cy);
        const float pz = fmaf(dz, d, cz);
        const float fx = fmaf(px, 128.0f, 127.5f);
        const float fy = fmaf(py, 128.0f, 127.5f);
        const float fz = fmaf(pz, 128.0f, 127.5f);

        // Outside coverage window on any axis -> dens=0, feat=0 (absorb *= 1).
        if (fx <= -1.0f || fx >= 256.0f || fy <= -1.0f || fy >= 256.0f ||
            fz <= -1.0f || fz >= 256.0f)
            continue;

        const float fx0 = floorf(fx), fy0 = floorf(fy), fz0 = floorf(fz);
        const int x0 = (int)fx0, y0 = (int)fy0, z0 = (int)fz0;
        const float wx = fx - fx0, wy = fy - fy0, wz = fz - fz0;

        if ((unsigned)x0 < 255u && (unsigned)y0 < 255u && (unsigned)z0 < 255u) {
            // Fully interior: coverage == 1 on all axes -> dens = SCALING.
            const int base = (z0 << 16) + (y0 << 8) + x0;
            const float c000 = vol[base];
            const float c001 = vol[base + 1];
            const float c010 = vol[base + 256];
            const float c011 = vol[base + 257];
            const float c100 = vol[base + 65536];
            const float c101 = vol[base + 65537];
            const float c110 = vol[base + 65536 + 256];
            const float c111 = vol[base + 65536 + 257];
            const float f00 = fmaf(wx, c001 - c000, c000);
            const float f01 = fmaf(wx, c011 - c010, c010);
            const float f10 = fmaf(wx, c101 - c100, c100);
            const float f11 = fmaf(wx, c111 - c110, c110);
            const float f0  = fmaf(wy, f01 - f00, f00);
            const float f1  = fmaf(wy, f11 - f10, f10);
            const float feat = fmaf(wz, f1 - f0, f0);
            S = fmaf(SCALING * A, feat, S);
            A *= (1.0f - SCALING);
        } else {
            // Border: zero-pad corners, per-axis coverage.
            const int x1 = x0 + 1, y1 = y0 + 1, z1 = z0 + 1;
            const bool bx0 = (unsigned)x0 < 256u, bx1 = (unsigned)x1 < 256u;
            const bool by0 = (unsigned)y0 < 256u, by1 = (unsigned)y1 < 256u;
            const bool bz0 = (unsigned)z0 < 256u, bz1 = (unsigned)z1 < 256u;
            const int xc0 = min(max(x0, 0), 255), xc1 = min(max(x1, 0), 255);
            const int yc0 = min(max(y0, 0), 255), yc1 = min(max(y1, 0), 255);
            const int zc0 = min(max(z0, 0), 255), zc1 = min(max(z1, 0), 255);
            const int zy00 = (zc0 << 16) + (yc0 << 8);
            const int zy01 = (zc0 << 16) + (yc1 << 8);
            const int zy10 = (zc1 << 16) + (yc0 << 8);
            const int zy11 = (zc1 << 16) + (yc1 << 8);
            const float c000 = (bz0 && by0 && bx0) ? vol[zy00 + xc0] : 0.0f;
            const float c001 = (bz0 && by0 && bx1) ? vol[zy00 + xc1] : 0.0f;
            const float c010 = (bz0 && by1 && bx0) ? vol[zy01 + xc0] : 0.0f;
            const float c011 = (bz0 && by1 && bx1) ? vol[zy01 + xc1] : 0.0f;
            const float c100 = (bz1 && by0 && bx0) ? vol[zy10 + xc0] : 0.0f;
            const float c101 = (bz1 && by0 && bx1) ? vol[zy10 + xc1] : 0.0f;
            const float c110 = (bz1 && by1 && bx0) ? vol[zy11 + xc0] : 0.0f;
            const float c111 = (bz1 && by1 && bx1) ? vol[zy11 + xc1] : 0.0f;
            const float f00 = fmaf(wx, c001 - c000, c000);
            const float f01 = fmaf(wx, c011 - c010, c010);
            const float f10 = fmaf(wx, c101 - c100, c100);
            const float f11 = fmaf(wx, c111 - c110, c110);
            const float f0  = fmaf(wy, f01 - f00, f00);
            const float f1  = fmaf(wy, f11 - f10, f10);
            const float feat = fmaf(wz, f1 - f0, f0);
            const float covx = (1.0f - wx) * (float)bx0 + wx * (float)bx1;
            const float covy = (1.0f - wy) * (float)by0 + wy * (float)by1;
            const float covz = (1.0f - wz) * (float)bz0 + wz * (float)bz1;
            const float dens = SCALING * covx * covy * covz;
            S = fmaf(dens * A, feat, S);
            A *= (1.0f - dens);
        }
    }

    Ssh[seg][tx] = S;
    Ash[seg][tx] = A;
    __syncthreads();

    if (seg == 0) {
        float rgb = 0.0f, Ap = 1.0f;
        #pragma unroll
        for (int s = 0; s < NSEG; ++s) {
            rgb = fmaf(Ap, Ssh[s][tx], rgb);
            Ap *= Ash[s][tx];
        }
        const float gray = fmaf(3.0f, rgb, 1.0f - Ap) * 0.25f;
        gray_out[w * IMG + h] = gray;      // output is transposed (0,2,1)
    }
}

// Stage 2: 64 partial maxes, one per block (plain stores only — no atomics,
// no cross-kernel RMW-visibility dependence; fmaxf is exactly order-invariant).
__global__ __launch_bounds__(256)
void maxred_kernel(const float* __restrict__ gray, float* __restrict__ part)
{
    const int tid = threadIdx.x;
    const float4 v = ((const float4*)gray)[blockIdx.x * 256 + tid];
    float m = fmaxf(fmaxf(v.x, v.y), fmaxf(v.z, v.w));
    #pragma unroll
    for (int off = 32; off; off >>= 1)
        m = fmaxf(m, __shfl_xor(m, off));
    __shared__ float ms[4];
    if ((tid & 63) == 0) ms[tid >> 6] = m;
    __syncthreads();
    if (tid == 0)
        part[blockIdx.x] = fmaxf(fmaxf(ms[0], ms[1]), fmaxf(ms[2], ms[3]));
}

// Stage 3: every wave loads all 64 partials (L2-broadcast), butterfly-max,
// then normalizes its pixels. part[] is fully rewritten by maxred every call.
__global__ __launch_bounds__(1024)
void norm_kernel(float* __restrict__ out, const float* __restrict__ part)
{
    float m = part[threadIdx.x & 63];
    #pragma unroll
    for (int off = 32; off; off >>= 1)
        m = fmaxf(m, __shfl_xor(m, off));
    const int i = blockIdx.x * 1024 + threadIdx.x;
    out[i] = (out[i] + EPS_MIN) / (m + EPS_MIN);
}

extern "C" void kernel_launch(void* const* d_in, const int* in_sizes, int n_in,
                              void* d_out, int out_size, void* d_ws, size_t ws_size,
                              hipStream_t stream) {
    const float* vol     = (const float*)d_in[0];
    const float* cam_rot = (const float*)d_in[1];
    const float* cam_pos = (const float*)d_in[2];
    float* out  = (float*)d_out;
    float* part = (float*)d_ws;    // 64 floats, fully rewritten every call

    dim3 block(64, NSEG);
    dim3 grid(IMG / 64, IMG);
    render_kernel<<<grid, block, 0, stream>>>(vol, cam_rot, cam_pos, out);
    maxred_kernel<<<64, 256, 0, stream>>>(out, part);
    norm_kernel<<<IMG * IMG / 1024, 1024, 0, stream>>>(out, part);
}

// Round 6
// 25.707 us; speedup vs baseline: 1.7722x; 1.0319x over previous
//
#include <hip/hip_runtime.h>

namespace {
constexpr int IMG = 256;
constexpr int NPTS = 320;
constexpr int NSEG = 16;
constexpr float MIN_D = 3.0f;
constexpr float STEP = 6.0f / 319.0f;   // linspace(3,9,320) step
constexpr float EPS_MIN = 1e-8f;
constexpr float SCALING = 0.1f;
}

// Branch-free interior step: all 8 corners in-bounds, coverage == 1.
__device__ __forceinline__ void interior_step(const float* __restrict__ vol,
                                              float fx, float fy, float fz,
                                              float& S, float& A)
{
    const float fx0 = floorf(fx), fy0 = floorf(fy), fz0 = floorf(fz);
    const int x0 = (int)fx0, y0 = (int)fy0, z0 = (int)fz0;
    const float wx = fx - fx0, wy = fy - fy0, wz = fz - fz0;
    const int base = (z0 << 16) + (y0 << 8) + x0;
    const float c000 = vol[base];
    const float c001 = vol[base + 1];
    const float c010 = vol[base + 256];
    const float c011 = vol[base + 257];
    const float c100 = vol[base + 65536];
    const float c101 = vol[base + 65537];
    const float c110 = vol[base + 65536 + 256];
    const float c111 = vol[base + 65536 + 257];
    const float f00 = fmaf(wx, c001 - c000, c000);
    const float f01 = fmaf(wx, c011 - c010, c010);
    const float f10 = fmaf(wx, c101 - c100, c100);
    const float f11 = fmaf(wx, c111 - c110, c110);
    const float f0  = fmaf(wy, f01 - f00, f00);
    const float f1  = fmaf(wy, f11 - f10, f10);
    const float feat = fmaf(wz, f1 - f0, f0);
    S = fmaf(SCALING * A, feat, S);
    A *= (1.0f - SCALING);
}

// General step: full window guard + zero-pad/coverage logic (exact path).
__device__ __forceinline__ void general_step(const float* __restrict__ vol,
                                             float fx, float fy, float fz,
                                             float& S, float& A)
{
    if (fx <= -1.0f || fx >= 256.0f || fy <= -1.0f || fy >= 256.0f ||
        fz <= -1.0f || fz >= 256.0f)
        return;                                  // dens=0, feat=0, absorb *= 1

    const float fx0 = floorf(fx), fy0 = floorf(fy), fz0 = floorf(fz);
    const int x0 = (int)fx0, y0 = (int)fy0, z0 = (int)fz0;
    const float wx = fx - fx0, wy = fy - fy0, wz = fz - fz0;

    if ((unsigned)x0 < 255u && (unsigned)y0 < 255u && (unsigned)z0 < 255u) {
        interior_step_body:;
        const int base = (z0 << 16) + (y0 << 8) + x0;
        const float c000 = vol[base];
        const float c001 = vol[base + 1];
        const float c010 = vol[base + 256];
        const float c011 = vol[base + 257];
        const float c100 = vol[base + 65536];
        const float c101 = vol[base + 65537];
        const float c110 = vol[base + 65536 + 256];
        const float c111 = vol[base + 65536 + 257];
        const float f00 = fmaf(wx, c001 - c000, c000);
        const float f01 = fmaf(wx, c011 - c010, c010);
        const float f10 = fmaf(wx, c101 - c100, c100);
        const float f11 = fmaf(wx, c111 - c110, c110);
        const float f0  = fmaf(wy, f01 - f00, f00);
        const float f1  = fmaf(wy, f11 - f10, f10);
        const float feat = fmaf(wz, f1 - f0, f0);
        S = fmaf(SCALING * A, feat, S);
        A *= (1.0f - SCALING);
    } else {
        const int x1 = x0 + 1, y1 = y0 + 1, z1 = z0 + 1;
        const bool bx0 = (unsigned)x0 < 256u, bx1 = (unsigned)x1 < 256u;
        const bool by0 = (unsigned)y0 < 256u, by1 = (unsigned)y1 < 256u;
        const bool bz0 = (unsigned)z0 < 256u, bz1 = (unsigned)z1 < 256u;
        const int xc0 = min(max(x0, 0), 255), xc1 = min(max(x1, 0), 255);
        const int yc0 = min(max(y0, 0), 255), yc1 = min(max(y1, 0), 255);
        const int zc0 = min(max(z0, 0), 255), zc1 = min(max(z1, 0), 255);
        const int zy00 = (zc0 << 16) + (yc0 << 8);
        const int zy01 = (zc0 << 16) + (yc1 << 8);
        const int zy10 = (zc1 << 16) + (yc0 << 8);
        const int zy11 = (zc1 << 16) + (yc1 << 8);
        const float c000 = (bz0 && by0 && bx0) ? vol[zy00 + xc0] : 0.0f;
        const float c001 = (bz0 && by0 && bx1) ? vol[zy00 + xc1] : 0.0f;
        const float c010 = (bz0 && by1 && bx0) ? vol[zy01 + xc0] : 0.0f;
        const float c011 = (bz0 && by1 && bx1) ? vol[zy01 + xc1] : 0.0f;
        const float c100 = (bz1 && by0 && bx0) ? vol[zy10 + xc0] : 0.0f;
        const float c101 = (bz1 && by0 && bx1) ? vol[zy10 + xc1] : 0.0f;
        const float c110 = (bz1 && by1 && bx0) ? vol[zy11 + xc0] : 0.0f;
        const float c111 = (bz1 && by1 && bx1) ? vol[zy11 + xc1] : 0.0f;
        const float f00 = fmaf(wx, c001 - c000, c000);
        const float f01 = fmaf(wx, c011 - c010, c010);
        const float f10 = fmaf(wx, c101 - c100, c100);
        const float f11 = fmaf(wx, c111 - c110, c110);
        const float f0  = fmaf(wy, f01 - f00, f00);
        const float f1  = fmaf(wy, f11 - f10, f10);
        const float feat = fmaf(wz, f1 - f0, f0);
        const float covx = (1.0f - wx) * (float)bx0 + wx * (float)bx1;
        const float covy = (1.0f - wy) * (float)by0 + wy * (float)by1;
        const float covz = (1.0f - wz) * (float)bz0 + wz * (float)bz1;
        const float dens = SCALING * covx * covy * covz;
        S = fmaf(dens * A, feat, S);
        A *= (1.0f - dens);
    }
}

// Block: (64 w-lanes, 16 ray-segments). Per ray: analytic slab split of the
// step range into [general | branch-free interior | general]; segments combine
// via the product-scan identity in LDS; seg-0 wave also reduces its 64 pixels'
// max and writes one partial per block (no atomics anywhere).
__global__ __launch_bounds__(1024, 8)
void render_kernel(const float* __restrict__ vol,
                   const float* __restrict__ cam_rot,
                   const float* __restrict__ cam_pos,
                   float* __restrict__ gray_out,
                   float* __restrict__ part)
{
    __shared__ float Ssh[NSEG][64];
    __shared__ float Ash[NSEG][64];

    const int tx  = threadIdx.x;
    const int seg = threadIdx.y;
    const int w   = blockIdx.x * 64 + tx;
    const int h   = blockIdx.y;

    const float gx = -1.0f + 2.0f * (float)w * (1.0f / 255.0f);
    const float gy = -1.0f + 2.0f * (float)h * (1.0f / 255.0f);
    const float dcx = gx * (1.0f / 3.0f);
    const float dcy = gy * (1.0f / 3.0f);

    const float dx = cam_rot[0] * dcx + cam_rot[1] * dcy + cam_rot[2];
    const float dy = cam_rot[3] * dcx + cam_rot[4] * dcy + cam_rot[5];
    const float dz = cam_rot[6] * dcx + cam_rot[7] * dcy + cam_rot[8];
    const float cx = cam_pos[0], cy = cam_pos[1], cz = cam_pos[2];

    // f_a(k) = B_a + A_a*k. Coverage: f in (-1,256); interior: f in [0,255).
    float klo_f = 0.0f, khi_f = (float)NPTS;
    float ilo_f = 0.0f, ihi_f = (float)NPTS;
    {
        const float Aax[3] = { dx * (STEP * 128.0f),
                               dy * (STEP * 128.0f),
                               dz * (STEP * 128.0f) };
        const float Bax[3] = { fmaf(fmaf(dx, MIN_D, cx), 128.0f, 127.5f),
                               fmaf(fmaf(dy, MIN_D, cy), 128.0f, 127.5f),
                               fmaf(fmaf(dz, MIN_D, cz), 128.0f, 127.5f) };
        #pragma unroll
        for (int a = 0; a < 3; ++a) {
            const float Aa = Aax[a], Ba = Bax[a];
            if (fabsf(Aa) < 1e-12f) {
                if (Ba <= -1.0f || Ba >= 256.0f) { klo_f = 1.0f; khi_f = 0.0f; }
                if (Ba <   0.0f || Ba >= 255.0f) { ilo_f = 1.0f; ihi_f = 0.0f; }
            } else {
                const float r = 1.0f / Aa;
                const float k1 = (-1.0f  - Ba) * r;
                const float k2 = (256.0f - Ba) * r;
                klo_f = fmaxf(klo_f, fminf(k1, k2));
                khi_f = fminf(khi_f, fmaxf(k1, k2));
                const float j1 = (0.0f   - Ba) * r;
                const float j2 = (255.0f - Ba) * r;
                ilo_f = fmaxf(ilo_f, fminf(j1, j2));
                ihi_f = fminf(ihi_f, fmaxf(j1, j2));
            }
        }
    }
    const int klo = max(0, (int)floorf(klo_f) - 1);
    const int khi = min(NPTS, (int)ceilf(khi_f) + 2);
    int ilo = (int)ceilf(ilo_f) + 1;           // 1-step safety margin; margin
    int ihi = (int)floorf(ihi_f) - 1;          // steps go through general path
    if (ihi < ilo) { ilo = klo; ihi = klo; }   // no interior

    const int n_active = max(0, khi - klo);
    const int per = (n_active + NSEG - 1) / NSEG;
    const int ks  = klo + seg * per;
    const int ke  = min(ks + per, khi);

    // [ks,i0) general, [i0,i1) interior (branch-free), [i1,ke) general
    const int i0 = min(max(ilo, ks), ke);
    const int i1 = min(max(ihi, i0), ke);

    float S = 0.0f;
    float A = 1.0f;

    for (int k = ks; k < i0; ++k) {
        const float d = fmaf((float)k, STEP, MIN_D);
        general_step(vol,
                     fmaf(fmaf(dx, d, cx), 128.0f, 127.5f),
                     fmaf(fmaf(dy, d, cy), 128.0f, 127.5f),
                     fmaf(fmaf(dz, d, cz), 128.0f, 127.5f), S, A);
    }
    #pragma unroll 2
    for (int k = i0; k < i1; ++k) {
        const float d = fmaf((float)k, STEP, MIN_D);
        interior_step(vol,
                      fmaf(fmaf(dx, d, cx), 128.0f, 127.5f),
                      fmaf(fmaf(dy, d, cy), 128.0f, 127.5f),
                      fmaf(fmaf(dz, d, cz), 128.0f, 127.5f), S, A);
    }
    for (int k = i1; k < ke; ++k) {
        const float d = fmaf((float)k, STEP, MIN_D);
        general_step(vol,
                     fmaf(fmaf(dx, d, cx), 128.0f, 127.5f),
                     fmaf(fmaf(dy, d, cy), 128.0f, 127.5f),
                     fmaf(fmaf(dz, d, cz), 128.0f, 127.5f), S, A);
    }

    Ssh[seg][tx] = S;
    Ash[seg][tx] = A;
    __syncthreads();

    if (seg == 0) {
        float rgb = 0.0f, Ap = 1.0f;
        #pragma unroll
        for (int s = 0; s < NSEG; ++s) {
            rgb = fmaf(Ap, Ssh[s][tx], rgb);
            Ap *= Ash[s][tx];
        }
        const float gray = fmaf(3.0f, rgb, 1.0f - Ap) * 0.25f;
        gray_out[w * IMG + h] = gray;      // output is transposed (0,2,1)

        float m = gray;                    // per-block max partial (64 pixels)
        #pragma unroll
        for (int off = 32; off; off >>= 1)
            m = fmaxf(m, __shfl_xor(m, off));
        if (tx == 0)
            part[blockIdx.y * (IMG / 64) + blockIdx.x] = m;
    }
}

// part[] has 1024 entries, fully rewritten by render every call. Each block
// reduces all partials (wave shuffle + LDS) and normalizes 1024 pixels.
__global__ __launch_bounds__(1024)
void norm_kernel(float* __restrict__ out, const float* __restrict__ part)
{
    const int t = threadIdx.x;
    float m = part[t];
    #pragma unroll
    for (int off = 32; off; off >>= 1)
        m = fmaxf(m, __shfl_xor(m, off));
    __shared__ float ws[16];
    if ((t & 63) == 0) ws[t >> 6] = m;
    __syncthreads();
    float g = ws[0];
    #pragma unroll
    for (int s = 1; s < 16; ++s) g = fmaxf(g, ws[s]);
    const int i = blockIdx.x * 1024 + t;
    out[i] = (out[i] + EPS_MIN) / (g + EPS_MIN);
}

extern "C" void kernel_launch(void* const* d_in, const int* in_sizes, int n_in,
                              void* d_out, int out_size, void* d_ws, size_t ws_size,
                              hipStream_t stream) {
    const float* vol     = (const float*)d_in[0];
    const float* cam_rot = (const float*)d_in[1];
    const float* cam_pos = (const float*)d_in[2];
    float* out  = (float*)d_out;
    float* part = (float*)d_ws;    // 1024 floats, fully rewritten every call

    dim3 block(64, NSEG);
    dim3 grid(IMG / 64, IMG);
    render_kernel<<<grid, block, 0, stream>>>(vol, cam_rot, cam_pos, out, part);
    norm_kernel<<<IMG * IMG / 1024, 1024, 0, stream>>>(out, part);
}